// Round 2
// baseline (651.655 us; speedup 1.0000x reference)
//
#include <hip/hip_runtime.h>
#include <hip/hip_bf16.h>
#include <utility>

// ---------------------------------------------------------------------------
// BatteriesInteractionBlock: equivariant tensor-product message passing.
//   N=10000 nodes, E=160000 edges, C=32 channels, 16 irreps (L_MAX=3),
//   34 CG paths, scatter-sum over dst, then 512x512 linear. Output f32.
//
//   prep_cg   : compute real Clebsch-Gordan blocks (3436 coeffs) on device
//   prep_w    : tp_weights -> bf16 transposed wt[p][d][c];
//               linear_w  -> bf16 remapped Wb[o][ia], ia = k*32 + c
//   edge_kernel: per 16-edge block: Y, gather x into regs, per path:
//               B=Y*cg (LDS) -> a = x.B (regs->bf16 LDS, MFMA-A layout)
//               -> mfma_f32_16x16x32_bf16 with weight frags; atomic scatter
//               into acc[dst][k][c] (fp32, d_ws)
//   lin_kernel: bf16 MFMA GEMM acc @ Wb^T + bias -> f32 out
// ---------------------------------------------------------------------------

#define NPATH 34
#define TOTCG 3436

typedef __attribute__((ext_vector_type(4))) float f32x4;
typedef __attribute__((ext_vector_type(8))) short short8;

// path tables: (l1,l2,l3) in reference order
constexpr int PL1[NPATH] = {0,0,0,0, 1,1,1,1,1,1,1,1,1, 2,2,2,2,2,2,2,2,2,2,2, 3,3,3,3,3,3,3,3,3,3};
constexpr int PL2[NPATH] = {0,1,2,3, 0,1,1,1,2,2,2,3,3, 0,1,1,1,2,2,2,2,3,3,3, 0,1,1,2,2,2,3,3,3,3};
constexpr int PL3[NPATH] = {0,1,2,3, 1,0,1,2,1,2,3,2,3, 2,1,2,3,0,1,2,3,1,2,3, 3,2,3,1,2,3,0,1,2,3};
// dense cg block offsets (size (2l1+1)(2l2+1)(2l3+1), layout [i][j][k])
constexpr int PCGO[NPATH] = {0,1,10,35, 84,93,102,129,174,219,294,399,504,
                             651,676,721,796,901,926,1001,1126,1301,1406,1581,
                             1826,1875,1980,2127,2232,2407,2652,2701,2848,3093};

__device__ __forceinline__ short f2bf(float f){
  unsigned u = __float_as_uint(f);
  unsigned r = (u + 0x7fffu + ((u >> 16) & 1u)) >> 16;
  return (short)r;
}

// ------------------------------ prep_cg ------------------------------------
__device__ double factd(int n){
  double f = 1.0;
  for (int i = 2; i <= n; i++) f *= (double)i;
  return f;
}

__device__ double cg_complex(int j1,int m1,int j2,int m2,int j3,int m3){
  if (m1 + m2 != m3) return 0.0;
  int dj = j1 - j2; if (dj < 0) dj = -dj;
  if (j3 < dj || j3 > j1 + j2) return 0.0;
  double pre = sqrt((double)(2*j3+1) * factd(j3+j1-j2) * factd(j3-j1+j2) *
                    factd(j1+j2-j3) / factd(j1+j2+j3+1));
  pre *= sqrt(factd(j3+m3)*factd(j3-m3)*factd(j1-m1)*factd(j1+m1)*
              factd(j2-m2)*factd(j2+m2));
  int k0 = 0;
  if (j2-j3-m1 > k0) k0 = j2-j3-m1;
  if (j1+m2-j3 > k0) k0 = j1+m2-j3;
  int k1 = j1+j2-j3;
  if (j1-m1 < k1) k1 = j1-m1;
  if (j2+m2 < k1) k1 = j2+m2;
  double s = 0.0;
  for (int k = k0; k <= k1; k++){
    double d = factd(k)*factd(j1+j2-j3-k)*factd(j1-m1-k)*factd(j2+m2-k)*
               factd(j3-j2+m1+k)*factd(j3-j1-m2+k);
    s += ((k & 1) ? -1.0 : 1.0) / d;
  }
  return pre * s;
}

struct Uent { int m; double re, im; };

// nonzeros of row a of the real->complex U(l) matrix (at most 2)
__device__ int urow(int l, int a, Uent* o){
  const double s2 = 0.70710678118654752440;
  int ra = a - l;
  if (ra == 0){ o[0] = {0, 1.0, 0.0}; return 1; }
  if (ra > 0){
    int m = ra;
    o[0] = { -m, s2, 0.0 };
    o[1] = {  m, (m & 1) ? -s2 : s2, 0.0 };
    return 2;
  }
  int m = -ra;
  o[0] = { -m, 0.0, s2 };
  o[1] = {  m, 0.0, (m & 1) ? s2 : -s2 };
  return 2;
}

__global__ void prep_cg(float* __restrict__ cgw){
  int idx = blockIdx.x * blockDim.x + threadIdx.x;
  if (idx >= TOTCG) return;
  int p = 0;
  for (int q = 1; q < NPATH; q++) if (idx >= PCGO[q]) p = q;
  const int l1 = PL1[p], l2 = PL2[p], l3 = PL3[p];
  const int S2 = 2*l2+1, S3 = 2*l3+1;
  int loc = idx - PCGO[p];
  int i = loc / (S2*S3);
  int r = loc - i*(S2*S3);
  int j = r / S3;
  int k = r - j*S3;
  Uent u1[2], u2[2], u3[2];
  int n1 = urow(l1, i, u1), n2 = urow(l2, j, u2), n3 = urow(l3, k, u3);
  double sre = 0.0, sim = 0.0;
  for (int a = 0; a < n1; a++)
    for (int b = 0; b < n2; b++)
      for (int c = 0; c < n3; c++){
        double cr = u1[a].re*u2[b].re - u1[a].im*u2[b].im;
        double ci = u1[a].re*u2[b].im + u1[a].im*u2[b].re;
        // times conj(u3)
        double tr = cr*u3[c].re + ci*u3[c].im;
        double ti = ci*u3[c].re - cr*u3[c].im;
        double cgv = cg_complex(l1, u1[a].m, l2, u2[b].m, l3, u3[c].m);
        sre += tr*cgv; sim += ti*cgv;
      }
  double v = (((l1+l2+l3) & 1) == 0) ? sre : sim;
  cgw[idx] = (float)v;
}

// ------------------------------ prep_w -------------------------------------
// wt[p][d][c] = bf16(tpw[p][c][d]);  Wb[o][ia] = bf16(W[o][(ia&31)*16 + (ia>>5)])
__global__ void prep_w(const float* __restrict__ tpw, const float* __restrict__ lw,
                       short* __restrict__ wt, short* __restrict__ Wb){
  int idx = blockIdx.x * blockDim.x + threadIdx.x;
  if (idx < NPATH*1024){
    int c = idx & 31, d = (idx >> 5) & 31, p = idx >> 10;
    wt[idx] = f2bf(tpw[(p << 10) + c*32 + d]);
  } else if (idx < NPATH*1024 + 512*512){
    int q = idx - NPATH*1024;
    int o = q >> 9, ia = q & 511;
    Wb[q] = f2bf(lw[o*512 + ((ia & 31) << 4) + (ia >> 5)]);
  }
}

// --------------------------- path expansion helper -------------------------
template<typename F, size_t... I>
__device__ __forceinline__ void for_each_path(F&& f, std::index_sequence<I...>){
  (f(std::integral_constant<size_t, I>{}), ...);
}

// ------------------------------ edge kernel --------------------------------
// block = 256 threads (4 waves), 16 edges per block.
// wave w: d-tile dt = w>>1, k-parity par = w&1
__global__ __launch_bounds__(256, 2) void edge_kernel(
    const float* __restrict__ nf, const int* __restrict__ ei,
    const float* __restrict__ ev, const float* __restrict__ cgw,
    const short* __restrict__ wt, float* __restrict__ accb,
    int E, int N)
{
  __shared__ float Yl[16][16];
  __shared__ int   sdst[16];
  __shared__ __align__(16) float Bp[16][7][8];          // [e][k][i(pad8)]
  __shared__ __align__(16) short a_lds[7][4][16][8];    // [k][c/8][e][c%8] bf16

  const int t    = threadIdx.x;
  const int lane = t & 63;
  const int wv   = t >> 6;
  const int dt   = wv >> 1;
  const int par  = wv & 1;
  const int eloc = t >> 4;     // 0..15 edge slot
  const int c0   = t & 15;     // thread covers channels c0 and c0+16
  const int e0   = blockIdx.x * 16;

  // ---- phase 0: Y + dst (first 16 threads) ----
  if (t < 16){
    int eg = e0 + t;
    float vx = 0.f, vy = 0.f, vz = 0.f; int dn = -1;
    if (eg < E){
      vx = ev[eg*3]; vy = ev[eg*3+1]; vz = ev[eg*3+2];
      dn = ei[E + eg];
    }
    float nrm = sqrtf(vx*vx + vy*vy + vz*vz);
    float inv = 1.0f / fmaxf(nrm, 1e-8f);
    float x = vx*inv, y = vy*inv, z = vz*inv;
    float x2 = x*x, y2 = y*y, z2 = z*z;
    Yl[t][0]  = 0.28209479177387814f;
    Yl[t][1]  = 0.4886025119029199f * y;
    Yl[t][2]  = 0.4886025119029199f * z;
    Yl[t][3]  = 0.4886025119029199f * x;
    Yl[t][4]  = 1.0925484305920792f * x * y;
    Yl[t][5]  = 1.0925484305920792f * y * z;
    Yl[t][6]  = 0.31539156525252005f * (3.f*z2 - 1.f);
    Yl[t][7]  = 1.0925484305920792f * x * z;
    Yl[t][8]  = 0.5462742152960396f * (x2 - y2);
    Yl[t][9]  = 0.5900435899266435f * y * (3.f*x2 - y2);
    Yl[t][10] = 2.890611442640554f * x * y * z;
    Yl[t][11] = 0.4570457994644658f * y * (5.f*z2 - 1.f);
    Yl[t][12] = 0.3731763325901154f * z * (5.f*z2 - 3.f);
    Yl[t][13] = 0.4570457994644658f * x * (5.f*z2 - 1.f);
    Yl[t][14] = 1.445305721320277f * z * (x2 - y2);
    Yl[t][15] = 0.5900435899266435f * x * (x2 - 3.f*y2);
    sdst[t] = dn;
  }

  // ---- phase 0b: gather x[src] into registers (2 channels x 16 irreps) ----
  float xr0[16], xr1[16];
  {
    int eg = e0 + eloc;
    int s = (eg < E) ? ei[eg] : 0;
    const float* xb = nf + (size_t)s * 512;
    #pragma unroll
    for (int q = 0; q < 4; q++){
      float4 v = ((const float4*)(xb + c0*16))[q];
      xr0[q*4+0] = v.x; xr0[q*4+1] = v.y; xr0[q*4+2] = v.z; xr0[q*4+3] = v.w;
      float4 w = ((const float4*)(xb + (c0+16)*16))[q];
      xr1[q*4+0] = w.x; xr1[q*4+1] = w.y; xr1[q*4+2] = w.z; xr1[q*4+3] = w.w;
    }
  }

  f32x4 accr[8];
  #pragma unroll
  for (int q = 0; q < 8; q++) accr[q] = (f32x4){0.f, 0.f, 0.f, 0.f};

  __syncthreads();

  auto pbody = [&](auto pc){
    constexpr int P   = (int)decltype(pc)::value;
    constexpr int L1v = PL1[P], L2v = PL2[P], L3v = PL3[P];
    constexpr int S1 = 2*L1v+1, S2 = 2*L2v+1, S3 = 2*L3v+1;
    constexpr int O1 = L1v*L1v, O2 = L2v*L2v, O3 = L3v*L3v;
    constexpr int CGO = PCGO[P];

    // B[e][k][i] = sum_j Y[e][O2+j] * cg[i][j][k]
    constexpr int NIT = 16*S3*S1;
    for (int it = t; it < NIT; it += 256){
      int e  = it / (S3*S1);
      int rr = it - e*(S3*S1);
      int kk = rr / S1;
      int i  = rr - kk*S1;
      float s = 0.f;
      #pragma unroll
      for (int j = 0; j < S2; j++)
        s += Yl[e][O2+j] * cgw[CGO + (i*S2 + j)*S3 + kk];
      Bp[e][kk][i] = s;
    }
    __syncthreads();

    // a[e][c][k] = sum_i x[e][c][O1+i] * B[e][k][i]  -> bf16 MFMA-A layout
    #pragma unroll
    for (int kk = 0; kk < S3; kk++){
      float bvs[8];
      *(float4*)&bvs[0] = *(const float4*)&Bp[eloc][kk][0];
      *(float4*)&bvs[4] = *(const float4*)&Bp[eloc][kk][4];
      float s0 = 0.f, s1 = 0.f;
      #pragma unroll
      for (int i = 0; i < S1; i++){
        s0 += xr0[O1+i]*bvs[i];
        s1 += xr1[O1+i]*bvs[i];
      }
      a_lds[kk][(c0>>3)    ][eloc][c0&7] = f2bf(s0);
      a_lds[kk][(c0>>3) + 2][eloc][c0&7] = f2bf(s1);
    }
    __syncthreads();

    // MFMA: C[e][d] += sum_c a[e][c] * w[c][d]  (one per k-row of this l3)
    {
      const short8 bw = *(const short8*)(wt +
          (size_t)(P*32 + dt*16 + (lane & 15))*32 + ((lane >> 4) * 8));
      #pragma unroll
      for (int kl = 0; kl < S3; kl++){
        if (((O3 + kl) & 1) == par){
          short8 af = *(const short8*)&a_lds[kl][lane >> 4][lane & 15][0];
          accr[(O3 + kl) >> 1] =
            __builtin_amdgcn_mfma_f32_16x16x32_bf16(af, bw, accr[(O3 + kl) >> 1], 0, 0, 0);
        }
      }
    }
    __syncthreads();
  };
  for_each_path(pbody, std::make_index_sequence<NPATH>{});

  // ---- epilogue: atomic scatter msg[e][d][k] -> acc[dst][k*32+d] ----
  const int d   = dt*16 + (lane & 15);
  const int eg4 = (lane >> 4) * 4;
  #pragma unroll
  for (int tix = 0; tix < 8; tix++){
    int kg = 2*tix + par;
    #pragma unroll
    for (int r = 0; r < 4; r++){
      int el = eg4 + r;
      int dn = sdst[el];
      if (dn >= 0)
        atomicAdd(accb + (size_t)dn*512 + (size_t)(kg*32 + d), accr[tix][r]);
    }
  }
}

// ------------------------------ linear kernel ------------------------------
// out[n][o] = sum_ia acc[n][ia] * Wb[o][ia] + bias[o]  (f32 out), 64x64 tiles
__global__ __launch_bounds__(256, 4) void lin_kernel(
    const float* __restrict__ accb, const short* __restrict__ Wb,
    const float* __restrict__ bias, float* __restrict__ out, int N)
{
  __shared__ __align__(16) short As[64][32];
  __shared__ __align__(16) short Ws[64][32];
  const int t = threadIdx.x;
  const int lane = t & 63, wv = t >> 6;
  const int n0 = blockIdx.x * 64, o0 = blockIdx.y * 64;
  f32x4 acc4[4];
  #pragma unroll
  for (int q = 0; q < 4; q++) acc4[q] = (f32x4){0.f, 0.f, 0.f, 0.f};

  const int nn = t >> 2, kq = (t & 3) * 8;
  for (int kc = 0; kc < 16; kc++){
    __syncthreads();
    {
      short8 v8;
      int gn = n0 + nn;
      if (gn < N){
        const float* sp = accb + (size_t)gn*512 + kc*32 + kq;
        float4 f0 = ((const float4*)sp)[0], f1 = ((const float4*)sp)[1];
        v8[0] = f2bf(f0.x); v8[1] = f2bf(f0.y); v8[2] = f2bf(f0.z); v8[3] = f2bf(f0.w);
        v8[4] = f2bf(f1.x); v8[5] = f2bf(f1.y); v8[6] = f2bf(f1.z); v8[7] = f2bf(f1.w);
      } else {
        #pragma unroll
        for (int q = 0; q < 8; q++) v8[q] = 0;
      }
      *(short8*)&As[nn][kq] = v8;
      *(short8*)&Ws[nn][kq] = *(const short8*)(Wb + (size_t)(o0 + nn)*512 + kc*32 + kq);
    }
    __syncthreads();
    const short8 af = *(const short8*)&As[wv*16 + (lane & 15)][(lane >> 4) * 8];
    #pragma unroll
    for (int ct = 0; ct < 4; ct++){
      short8 bf8 = *(const short8*)&Ws[ct*16 + (lane & 15)][(lane >> 4) * 8];
      acc4[ct] = __builtin_amdgcn_mfma_f32_16x16x32_bf16(af, bf8, acc4[ct], 0, 0, 0);
    }
  }

  #pragma unroll
  for (int ct = 0; ct < 4; ct++){
    int o = o0 + ct*16 + (lane & 15);
    float bb = bias[o];
    #pragma unroll
    for (int r = 0; r < 4; r++){
      int n = n0 + wv*16 + (lane >> 4)*4 + r;
      if (n < N)
        out[(size_t)n*512 + o] = acc4[ct][r] + bb;
    }
  }
}

// ------------------------------ launcher -----------------------------------
extern "C" void kernel_launch(void* const* d_in, const int* in_sizes, int n_in,
                              void* d_out, int out_size, void* d_ws, size_t ws_size,
                              hipStream_t stream) {
  const float* nf  = (const float*)d_in[0];   // node_features (N,32,16) f32
  const int*   ei  = (const int*)d_in[1];     // edge_index (2,E) i32
  const float* ev  = (const float*)d_in[2];   // edge_vectors (E,3) f32
  const float* tpw = (const float*)d_in[3];   // tp_weights (34,32,32) f32
  const float* lw  = (const float*)d_in[4];   // linear_w (512,512) f32
  const float* lb  = (const float*)d_in[5];   // linear_b (512,) f32

  const int N = in_sizes[0] / 512;
  const int E = in_sizes[1] / 2;

  char* ws = (char*)d_ws;
  size_t off = 0;
  float* accb = (float*)(ws + off);
  off += (size_t)N * 512 * 4;          off = (off + 255) & ~(size_t)255;
  float* cgw  = (float*)(ws + off);
  off += (size_t)TOTCG * 4;            off = (off + 255) & ~(size_t)255;
  short* wt   = (short*)(ws + off);
  off += (size_t)NPATH * 1024 * 2;     off = (off + 255) & ~(size_t)255;
  short* Wb   = (short*)(ws + off);
  off += (size_t)512 * 512 * 2;
  if (off > ws_size) return;  // workspace too small: fail loudly via validation

  hipMemsetAsync(accb, 0, (size_t)N * 512 * 4, stream);
  prep_cg<<<(TOTCG + 255) / 256, 256, 0, stream>>>(cgw);
  prep_w<<<(NPATH*1024 + 512*512 + 255) / 256, 256, 0, stream>>>(tpw, lw, wt, Wb);
  edge_kernel<<<(E + 15) / 16, 256, 0, stream>>>(nf, ei, ev, cgw, wt, accb, E, N);
  lin_kernel<<<dim3((N + 63) / 64, 8), 256, 0, stream>>>(accb, Wb, lb,
                                                         (float*)d_out, N);
}

// Round 3
// 480.753 us; speedup vs baseline: 1.3555x; 1.3555x over previous
//
#include <hip/hip_runtime.h>
#include <hip/hip_bf16.h>
#include <utility>

// ---------------------------------------------------------------------------
// BatteriesInteractionBlock: equivariant tensor-product message passing.
//   N=10000 nodes, E=160000 edges, C=32 channels, 16 irreps (L_MAX=3),
//   34 CG paths, scatter-sum over dst, then 512x512 linear. Output f32.
//
// Round-3 structure (from round-2 counters: VALUBusy 45%, 102 barriers/block,
// global cg loads in hot loop, scalar fp32 FMA):
//   prep_cgf  : real CG blocks in pair-padded [k][j][i] f32 layout (4174 el)
//   prep_w    : tp_weights -> bf16 wt[p][d][c]; linear_w -> bf16 Wb[o][k*32+c]
//   edge_kernel (256 thr / 16 edges):
//       cg staged in LDS; Y duplicated {y,y} for packed math
//       per path: wave-local B-comp (v_pk_fma over i-pairs, no barrier)
//                 a-comp: v_pk_fma over channel pairs w/ op_sel B-broadcast,
//                         v_cvt_pk_bf16_f32 -> ping-pong a_lds
//                 ONE __syncthreads -> MFMA 16x16x32 bf16 accumulate
//       epilogue: fp32 atomicAdd scatter into acc[dst][k*32+c]
//   lin_kernel: bf16 MFMA GEMM acc @ Wb^T + bias -> f32 out
// ---------------------------------------------------------------------------

#define NPATH 34
#define TOTCGF 4174

typedef __attribute__((ext_vector_type(2))) float f32x2;
typedef __attribute__((ext_vector_type(4))) float f32x4;
typedef __attribute__((ext_vector_type(8))) short short8;

// path tables: (l1,l2,l3) in reference order
constexpr int PL1[NPATH] = {0,0,0,0, 1,1,1,1,1,1,1,1,1, 2,2,2,2,2,2,2,2,2,2,2, 3,3,3,3,3,3,3,3,3,3};
constexpr int PL2[NPATH] = {0,1,2,3, 0,1,1,1,2,2,2,3,3, 0,1,1,1,2,2,2,2,3,3,3, 0,1,1,2,2,2,3,3,3,3};
constexpr int PL3[NPATH] = {0,1,2,3, 1,0,1,2,1,2,3,2,3, 2,1,2,3,0,1,2,3,1,2,3, 3,2,3,1,2,3,0,1,2,3};
// offsets into pair-padded cg: per path size S3*S2*(S1+1), layout [k][j][i(pad even)]
constexpr int PCGF[NPATH] = {0,2,20,70, 168,180,192,228,288,348,448,588,728,
                             924,954,1008,1098,1224,1254,1344,1494,1704,1830,2040,
                             2334,2390,2510,2678,2798,2998,3278,3334,3502,3782};

__device__ __forceinline__ short f2bf(float f){
  unsigned u = __float_as_uint(f);
  unsigned r = (u + 0x7fffu + ((u >> 16) & 1u)) >> 16;
  return (short)r;
}

// ---- packed-math helpers (VOP3P / VOP3) -----------------------------------
__device__ __forceinline__ f32x2 pk_fma(f32x2 a, f32x2 x, f32x2 b){
  // a.lo += x.lo*b.lo ; a.hi += x.hi*b.hi
  asm("v_pk_fma_f32 %0, %1, %2, %0" : "+v"(a) : "v"(x), "v"(b));
  return a;
}
__device__ __forceinline__ f32x2 pk_fma_blo(f32x2 a, f32x2 x, f32x2 b){
  // broadcast b.lo to both halves
  asm("v_pk_fma_f32 %0, %1, %2, %0 op_sel:[0,0,0] op_sel_hi:[1,0,1]"
      : "+v"(a) : "v"(x), "v"(b));
  return a;
}
__device__ __forceinline__ f32x2 pk_fma_bhi(f32x2 a, f32x2 x, f32x2 b){
  // broadcast b.hi to both halves
  asm("v_pk_fma_f32 %0, %1, %2, %0 op_sel:[0,1,0] op_sel_hi:[1,1,1]"
      : "+v"(a) : "v"(x), "v"(b));
  return a;
}
__device__ __forceinline__ unsigned cvt_pk_bf16(float lo, float hi){
  unsigned r;
  asm("v_cvt_pk_bf16_f32 %0, %1, %2" : "=v"(r) : "v"(lo), "v"(hi));
  return r;
}

// ------------------------------ prep_cgf -----------------------------------
__device__ double factd(int n){
  double f = 1.0;
  for (int i = 2; i <= n; i++) f *= (double)i;
  return f;
}

__device__ double cg_complex(int j1,int m1,int j2,int m2,int j3,int m3){
  if (m1 + m2 != m3) return 0.0;
  int dj = j1 - j2; if (dj < 0) dj = -dj;
  if (j3 < dj || j3 > j1 + j2) return 0.0;
  double pre = sqrt((double)(2*j3+1) * factd(j3+j1-j2) * factd(j3-j1+j2) *
                    factd(j1+j2-j3) / factd(j1+j2+j3+1));
  pre *= sqrt(factd(j3+m3)*factd(j3-m3)*factd(j1-m1)*factd(j1+m1)*
              factd(j2-m2)*factd(j2+m2));
  int k0 = 0;
  if (j2-j3-m1 > k0) k0 = j2-j3-m1;
  if (j1+m2-j3 > k0) k0 = j1+m2-j3;
  int k1 = j1+j2-j3;
  if (j1-m1 < k1) k1 = j1-m1;
  if (j2+m2 < k1) k1 = j2+m2;
  double s = 0.0;
  for (int k = k0; k <= k1; k++){
    double d = factd(k)*factd(j1+j2-j3-k)*factd(j1-m1-k)*factd(j2+m2-k)*
               factd(j3-j2+m1+k)*factd(j3-j1-m2+k);
    s += ((k & 1) ? -1.0 : 1.0) / d;
  }
  return pre * s;
}

struct Uent { int m; double re, im; };

__device__ int urow(int l, int a, Uent* o){
  const double s2 = 0.70710678118654752440;
  int ra = a - l;
  if (ra == 0){ o[0] = {0, 1.0, 0.0}; return 1; }
  if (ra > 0){
    int m = ra;
    o[0] = { -m, s2, 0.0 };
    o[1] = {  m, (m & 1) ? -s2 : s2, 0.0 };
    return 2;
  }
  int m = -ra;
  o[0] = { -m, 0.0, s2 };
  o[1] = {  m, 0.0, (m & 1) ? s2 : -s2 };
  return 2;
}

__device__ float real_cg(int l1, int l2, int l3, int i, int j, int k){
  Uent u1[2], u2[2], u3[2];
  int n1 = urow(l1, i, u1), n2 = urow(l2, j, u2), n3 = urow(l3, k, u3);
  double sre = 0.0, sim = 0.0;
  for (int a = 0; a < n1; a++)
    for (int b = 0; b < n2; b++)
      for (int c = 0; c < n3; c++){
        double cr = u1[a].re*u2[b].re - u1[a].im*u2[b].im;
        double ci = u1[a].re*u2[b].im + u1[a].im*u2[b].re;
        double tr = cr*u3[c].re + ci*u3[c].im;   // times conj(u3)
        double ti = ci*u3[c].re - cr*u3[c].im;
        double cgv = cg_complex(l1, u1[a].m, l2, u2[b].m, l3, u3[c].m);
        sre += tr*cgv; sim += ti*cgv;
      }
  return (float)((((l1+l2+l3) & 1) == 0) ? sre : sim);
}

// writes cgf[slot] with slot = PCGF[p] + (k*S2 + j)*(S1+1) + i  (i pad -> 0)
__global__ void prep_cgf(float* __restrict__ cgf){
  int idx = blockIdx.x * blockDim.x + threadIdx.x;
  if (idx >= TOTCGF) return;
  int p = 0;
  for (int q = 1; q < NPATH; q++) if (idx >= PCGF[q]) p = q;
  const int l1 = PL1[p], l2 = PL2[p], l3 = PL3[p];
  const int S1 = 2*l1+1, S2 = 2*l2+1, S1p = S1+1;
  int q  = idx - PCGF[p];
  int kkj = q / S1p;
  int ii  = q - kkj*S1p;
  int kk  = kkj / S2;
  int j   = kkj - kk*S2;
  float v = 0.f;
  if (ii < S1) v = real_cg(l1, l2, l3, ii, j, kk);
  cgf[idx] = v;
}

// ------------------------------ prep_w -------------------------------------
// wt[p][d][c] = bf16(tpw[p][c][d]);  Wb[o][ia] = bf16(W[o][(ia&31)*16 + (ia>>5)])
__global__ void prep_w(const float* __restrict__ tpw, const float* __restrict__ lw,
                       short* __restrict__ wt, short* __restrict__ Wb){
  int idx = blockIdx.x * blockDim.x + threadIdx.x;
  if (idx < NPATH*1024){
    int c = idx & 31, d = (idx >> 5) & 31, p = idx >> 10;
    wt[idx] = f2bf(tpw[(p << 10) + c*32 + d]);
  } else if (idx < NPATH*1024 + 512*512){
    int q = idx - NPATH*1024;
    int o = q >> 9, ia = q & 511;
    Wb[q] = f2bf(lw[o*512 + ((ia & 31) << 4) + (ia >> 5)]);
  }
}

// --------------------------- path expansion helper -------------------------
template<typename F, size_t... I>
__device__ __forceinline__ void for_each_path(F&& f, std::index_sequence<I...>){
  (f(std::integral_constant<size_t, I>{}), ...);
}

// ------------------------------ edge kernel --------------------------------
// 256 threads (4 waves), 16 edges/block. wave wv: dt = wv&1, par = wv>>1.
// Wave w owns edges 4w..4w+3 for B-comp and a-comp (wave-local, no barrier);
// one __syncthreads per path between a_lds write and MFMA read (ping-pong).
__global__ __launch_bounds__(256, 4) void edge_kernel(
    const float* __restrict__ nf, const int* __restrict__ ei,
    const float* __restrict__ ev, const float* __restrict__ cgfg,
    const short* __restrict__ wt, float* __restrict__ accb,
    int E, int N)
{
  __shared__ __align__(16) float cgf[TOTCGF];            // 16696 B
  __shared__ __align__(16) f32x2 Ydup[16][16];           //  2048 B ({y,y})
  __shared__ int   sdst[16];
  __shared__ __align__(16) float Bp[16][7][8];           //  3584 B [e][k][i]
  __shared__ __align__(16) short a_lds[2][7][4][16][8];  // 14336 B [buf][k][c/8][e][c%8]

  const int t    = threadIdx.x;
  const int lane = t & 63;
  const int wv   = t >> 6;
  const int dt   = wv & 1;
  const int par  = wv >> 1;
  const int eloc = t >> 4;     // 0..15 edge slot (wave-local: wv*4 + (lane>>4))
  const int c0   = t & 15;     // thread covers channels 2c0, 2c0+1
  const int e0   = blockIdx.x * 16;

  // ---- prologue: stage cg, Y (dup), dst, x-gather ----
  for (int i = t; i < TOTCGF; i += 256) cgf[i] = cgfg[i];

  if (t < 16){
    int eg = e0 + t;
    float vx = 0.f, vy = 0.f, vz = 0.f; int dn = -1;
    if (eg < E){
      vx = ev[eg*3]; vy = ev[eg*3+1]; vz = ev[eg*3+2];
      dn = ei[E + eg];
    }
    float nrm = sqrtf(vx*vx + vy*vy + vz*vz);
    float inv = 1.0f / fmaxf(nrm, 1e-8f);
    float x = vx*inv, y = vy*inv, z = vz*inv;
    float x2 = x*x, y2 = y*y, z2 = z*z;
    float ys[16];
    ys[0]  = 0.28209479177387814f;
    ys[1]  = 0.4886025119029199f * y;
    ys[2]  = 0.4886025119029199f * z;
    ys[3]  = 0.4886025119029199f * x;
    ys[4]  = 1.0925484305920792f * x * y;
    ys[5]  = 1.0925484305920792f * y * z;
    ys[6]  = 0.31539156525252005f * (3.f*z2 - 1.f);
    ys[7]  = 1.0925484305920792f * x * z;
    ys[8]  = 0.5462742152960396f * (x2 - y2);
    ys[9]  = 0.5900435899266435f * y * (3.f*x2 - y2);
    ys[10] = 2.890611442640554f * x * y * z;
    ys[11] = 0.4570457994644658f * y * (5.f*z2 - 1.f);
    ys[12] = 0.3731763325901154f * z * (5.f*z2 - 3.f);
    ys[13] = 0.4570457994644658f * x * (5.f*z2 - 1.f);
    ys[14] = 1.445305721320277f * z * (x2 - y2);
    ys[15] = 0.5900435899266435f * x * (x2 - 3.f*y2);
    #pragma unroll
    for (int j = 0; j < 16; j++) Ydup[t][j] = (f32x2){ys[j], ys[j]};
    sdst[t] = dn;
  }

  // x[src] channel pair (2c0, 2c0+1), 16 irreps each, interleaved pairs
  f32x2 xr[16];
  {
    int eg = e0 + eloc;
    int s = (eg < E) ? ei[eg] : 0;
    const float* xb = nf + (size_t)s * 512;
    f32x4 va[4], vb[4];
    #pragma unroll
    for (int q = 0; q < 4; q++){
      va[q] = ((const f32x4*)(xb + (2*c0)   * 16))[q];
      vb[q] = ((const f32x4*)(xb + (2*c0+1) * 16))[q];
    }
    #pragma unroll
    for (int q = 0; q < 4; q++)
      #pragma unroll
      for (int r = 0; r < 4; r++)
        xr[q*4+r] = (f32x2){va[q][r], vb[q][r]};
  }

  f32x4 accr[8];
  #pragma unroll
  for (int q = 0; q < 8; q++) accr[q] = (f32x4){0.f, 0.f, 0.f, 0.f};

  __syncthreads();

  auto pbody = [&](auto pc){
    constexpr int P   = (int)decltype(pc)::value;
    constexpr int L1v = PL1[P], L2v = PL2[P], L3v = PL3[P];
    constexpr int S1 = 2*L1v+1, S2 = 2*L2v+1, S3 = 2*L3v+1;
    constexpr int O1 = L1v*L1v, O2 = L2v*L2v, O3 = L3v*L3v;
    constexpr int S1p  = S1 + 1;        // even
    constexpr int S1p2 = S1p / 2;       // i-pairs
    constexpr int CGF  = PCGF[P];
    constexpr int BUF  = P & 1;

    // weight fragment (global, L2-hot): issue early
    const short8 bw = *(const short8*)(wt +
        (size_t)(P*32 + dt*16 + (lane & 15))*32 + ((lane >> 4) * 8));

    // ---- B-comp (wave-local): B[e][k][i-pair] = sum_j {cg_i,cg_i1}*{y,y} ----
    {
      const int wbase = wv * 4;
      constexpr int NITW = 4 * S3 * S1p2;
      for (int it = lane; it < NITW; it += 64){
        int el4 = it / (S3*S1p2);
        int rr  = it - el4*(S3*S1p2);
        int kk  = rr / S1p2;
        int p2  = rr - kk*S1p2;
        int e   = wbase + el4;
        f32x2 acc = {0.f, 0.f};
        #pragma unroll
        for (int j = 0; j < S2; j++){
          f32x2 c2 = *(const f32x2*)&cgf[CGF + (kk*S2 + j)*S1p + 2*p2];
          acc = pk_fma(acc, c2, Ydup[e][O2 + j]);
        }
        *(f32x2*)&Bp[e][kk][2*p2] = acc;
      }
    }
    // wave-local write->read: LDS in-order per wave, no barrier needed

    // ---- a-comp: acc{ca,cb} = sum_i xr[i] * B[i] (op_sel broadcast) ----
    #pragma unroll
    for (int kk = 0; kk < S3; kk++){
      f32x4 bv01 = *(const f32x4*)&Bp[eloc][kk][0];
      f32x2 pr[4];
      pr[0] = __builtin_shufflevector(bv01, bv01, 0, 1);
      pr[1] = __builtin_shufflevector(bv01, bv01, 2, 3);
      if constexpr (S1 > 4){
        f32x4 bv23 = *(const f32x4*)&Bp[eloc][kk][4];
        pr[2] = __builtin_shufflevector(bv23, bv23, 0, 1);
        pr[3] = __builtin_shufflevector(bv23, bv23, 2, 3);
      }
      f32x2 acc = {0.f, 0.f};
      #pragma unroll
      for (int i = 0; i < S1; i++){
        if ((i & 1) == 0) acc = pk_fma_blo(acc, xr[O1+i], pr[i>>1]);
        else              acc = pk_fma_bhi(acc, xr[O1+i], pr[i>>1]);
      }
      unsigned pk = cvt_pk_bf16(acc.x, acc.y);
      *(unsigned*)&a_lds[BUF][kk][c0 >> 2][eloc][(c0 & 3)*2] = pk;
    }
    __syncthreads();

    // ---- MFMA: C[e][d] += sum_c a[e][c] * w[c][d], parity-split over waves --
    #pragma unroll
    for (int kl = 0; kl < S3; kl++){
      if (((O3 + kl) & 1) == par){
        short8 af = *(const short8*)&a_lds[BUF][kl][lane >> 4][lane & 15][0];
        accr[(O3 + kl) >> 1] =
          __builtin_amdgcn_mfma_f32_16x16x32_bf16(af, bw, accr[(O3 + kl) >> 1], 0, 0, 0);
      }
    }
  };
  for_each_path(pbody, std::make_index_sequence<NPATH>{});

  // ---- epilogue: atomic scatter msg[e][d][k] -> acc[dst][k*32+d] ----
  const int d   = dt*16 + (lane & 15);
  const int eg4 = (lane >> 4) * 4;
  #pragma unroll
  for (int tix = 0; tix < 8; tix++){
    int kg = 2*tix + par;
    #pragma unroll
    for (int r = 0; r < 4; r++){
      int el = eg4 + r;
      int dn = sdst[el];
      if (dn >= 0)
        atomicAdd(accb + (size_t)dn*512 + (size_t)(kg*32 + d), accr[tix][r]);
    }
  }
}

// ------------------------------ linear kernel ------------------------------
// out[n][o] = sum_ia acc[n][ia] * Wb[o][ia] + bias[o]  (f32 out), 64x64 tiles
__global__ __launch_bounds__(256, 4) void lin_kernel(
    const float* __restrict__ accb, const short* __restrict__ Wb,
    const float* __restrict__ bias, float* __restrict__ out, int N)
{
  __shared__ __align__(16) short As[64][32];
  __shared__ __align__(16) short Ws[64][32];
  const int t = threadIdx.x;
  const int lane = t & 63, wv = t >> 6;
  const int n0 = blockIdx.x * 64, o0 = blockIdx.y * 64;
  f32x4 acc4[4];
  #pragma unroll
  for (int q = 0; q < 4; q++) acc4[q] = (f32x4){0.f, 0.f, 0.f, 0.f};

  const int nn = t >> 2, kq = (t & 3) * 8;
  for (int kc = 0; kc < 16; kc++){
    __syncthreads();
    {
      short8 v8;
      int gn = n0 + nn;
      if (gn < N){
        const float* sp = accb + (size_t)gn*512 + kc*32 + kq;
        f32x4 f0 = ((const f32x4*)sp)[0], f1 = ((const f32x4*)sp)[1];
        v8[0] = f2bf(f0[0]); v8[1] = f2bf(f0[1]); v8[2] = f2bf(f0[2]); v8[3] = f2bf(f0[3]);
        v8[4] = f2bf(f1[0]); v8[5] = f2bf(f1[1]); v8[6] = f2bf(f1[2]); v8[7] = f2bf(f1[3]);
      } else {
        #pragma unroll
        for (int q = 0; q < 8; q++) v8[q] = 0;
      }
      *(short8*)&As[nn][kq] = v8;
      *(short8*)&Ws[nn][kq] = *(const short8*)(Wb + (size_t)(o0 + nn)*512 + kc*32 + kq);
    }
    __syncthreads();
    const short8 af = *(const short8*)&As[wv*16 + (lane & 15)][(lane >> 4) * 8];
    #pragma unroll
    for (int ct = 0; ct < 4; ct++){
      short8 bf8 = *(const short8*)&Ws[ct*16 + (lane & 15)][(lane >> 4) * 8];
      acc4[ct] = __builtin_amdgcn_mfma_f32_16x16x32_bf16(af, bf8, acc4[ct], 0, 0, 0);
    }
  }

  #pragma unroll
  for (int ct = 0; ct < 4; ct++){
    int o = o0 + ct*16 + (lane & 15);
    float bb = bias[o];
    #pragma unroll
    for (int r = 0; r < 4; r++){
      int n = n0 + wv*16 + (lane >> 4)*4 + r;
      if (n < N)
        out[(size_t)n*512 + o] = acc4[ct][r] + bb;
    }
  }
}

// ------------------------------ launcher -----------------------------------
extern "C" void kernel_launch(void* const* d_in, const int* in_sizes, int n_in,
                              void* d_out, int out_size, void* d_ws, size_t ws_size,
                              hipStream_t stream) {
  const float* nf  = (const float*)d_in[0];   // node_features (N,32,16) f32
  const int*   ei  = (const int*)d_in[1];     // edge_index (2,E) i32
  const float* ev  = (const float*)d_in[2];   // edge_vectors (E,3) f32
  const float* tpw = (const float*)d_in[3];   // tp_weights (34,32,32) f32
  const float* lw  = (const float*)d_in[4];   // linear_w (512,512) f32
  const float* lb  = (const float*)d_in[5];   // linear_b (512,) f32

  const int N = in_sizes[0] / 512;
  const int E = in_sizes[1] / 2;

  char* ws = (char*)d_ws;
  size_t off = 0;
  float* accb = (float*)(ws + off);
  off += (size_t)N * 512 * 4;          off = (off + 255) & ~(size_t)255;
  float* cgfg = (float*)(ws + off);
  off += (size_t)TOTCGF * 4;           off = (off + 255) & ~(size_t)255;
  short* wt   = (short*)(ws + off);
  off += (size_t)NPATH * 1024 * 2;     off = (off + 255) & ~(size_t)255;
  short* Wb   = (short*)(ws + off);
  off += (size_t)512 * 512 * 2;
  if (off > ws_size) return;  // workspace too small: fail loudly via validation

  hipMemsetAsync(accb, 0, (size_t)N * 512 * 4, stream);
  prep_cgf<<<(TOTCGF + 255) / 256, 256, 0, stream>>>(cgfg);
  prep_w<<<(NPATH*1024 + 512*512 + 255) / 256, 256, 0, stream>>>(tpw, lw, wt, Wb);
  edge_kernel<<<(E + 15) / 16, 256, 0, stream>>>(nf, ei, ev, cgfg, wt, accb, E, N);
  lin_kernel<<<dim3((N + 63) / 64, 8), 256, 0, stream>>>(accb, Wb, lb,
                                                         (float*)d_out, N);
}